// Round 1
// baseline (158.734 us; speedup 1.0000x reference)
//
#include <hip/hip_runtime.h>

// LAYER_IDX = [0, 4096, 6144, 7168, 7680, 7682]
// L1: 4096->2048 ebase 0       | L2: 2048->1024 ebase 262144
// L3: 1024->512  ebase 393216  | out: 512->2    ebase 458752
// Sparse gather formulation: per target node, 128 edges; activations kept
// feature-major [node][512] so each edge is one contiguous coalesced row read.
#define BATCH 512
#define FAN_IN 128
#define EPS 1e-5f

typedef unsigned short u16;
typedef unsigned int u32;

__device__ __forceinline__ u16 f2bf(float f) {   // fp32->bf16 RNE
    union { float f; u32 u; } v; v.f = f;
    u32 r = v.u + 0x7fffu + ((v.u >> 16) & 1u);
    return (u16)(r >> 16);
}
__device__ __forceinline__ float bf2f(u16 h) {
    union { u32 u; float f; } v; v.u = ((u32)h) << 16; return v.f;
}

// ---------------------------------------------------------------------------
// K0: transpose x[512][4096] f32 -> xT[4096][512] bf16. Block 512 zeroes the
// LN-stats atomics buffer (workspace is re-poisoned by harness, can't assume 0).
__global__ __launch_bounds__(256) void prepk(
    const float* __restrict__ x, u16* __restrict__ xT,
    float* __restrict__ stats) {
    const int tid = threadIdx.x, bid = blockIdx.x;
    if (bid == 512) {
        for (int i = tid; i < 3072; i += 256) stats[i] = 0.f;
        return;
    }
    __shared__ float T[64][65];                  // +1 pad: conflict-free cols
    const int f0 = (bid & 63) * 64, b0 = (bid >> 6) * 64;
    const int r = tid >> 4, c4 = (tid & 15) * 4;
#pragma unroll
    for (int rr = 0; rr < 4; ++rr) {
        const int row = r + rr * 16;
        const float4 v = *(const float4*)(x + (size_t)(b0 + row) * 4096 + f0 + c4);
        T[row][c4] = v.x; T[row][c4 + 1] = v.y;
        T[row][c4 + 2] = v.z; T[row][c4 + 3] = v.w;
    }
    __syncthreads();
#pragma unroll
    for (int half = 0; half < 2; ++half) {
        const int fr = (tid >> 3) + half * 32;
        const int bq = (tid & 7) * 8;
        uint4 pk;
        pk.x = (u32)f2bf(T[bq + 0][fr]) | ((u32)f2bf(T[bq + 1][fr]) << 16);
        pk.y = (u32)f2bf(T[bq + 2][fr]) | ((u32)f2bf(T[bq + 3][fr]) << 16);
        pk.z = (u32)f2bf(T[bq + 4][fr]) | ((u32)f2bf(T[bq + 5][fr]) << 16);
        pk.w = (u32)f2bf(T[bq + 6][fr]) | ((u32)f2bf(T[bq + 7][fr]) << 16);
        *(uint4*)(xT + (size_t)(f0 + fr) * 512 + b0 + bq) = pk;
    }
}

// ---------------------------------------------------------------------------
// Sparse gather layer: one wave per (target node, batch-half of 256).
// Block = 4 node-waves sharing one batch-half. blockIdx%8 maps to XCD
// (dispatch round-robin heuristic): XCDs 0-3 take half 0, 4-7 take half 1,
// so each XCD's 4 MiB L2 only needs half the source panel (L1: 2.1 MB).
// Epilogue: +bias, write raw f32, LDS-reduce + global atomic colsum/colsumsq
// (LN stats are over nodes per batch column).
template <int NT, int EBASE, int SRCBASE>
__global__ __launch_bounds__(256) void gatherk(
    const u16* __restrict__ srcAct, const float* __restrict__ weight,
    const int* __restrict__ edge_src, const float* __restrict__ bias_l,
    float* __restrict__ raw, float* __restrict__ gcs,
    float* __restrict__ gcq) {
    __shared__ float cs[256];
    __shared__ float cq[256];
    const int tid = threadIdx.x, bid = blockIdx.x;
    const int rr = bid & 7, kk = bid >> 3;
    const int bc = rr >> 2;                    // batch half (XCD-partitioned)
    const int ng = kk * 4 + (rr & 3);          // node group, [0, NT/4)
    const int wave = __builtin_amdgcn_readfirstlane(tid >> 6);
    const int lane = tid & 63;
    const int node = ng * 4 + wave;
    const u16* sb = srcAct + bc * 256 + lane * 4;
    const int ebase = EBASE + node * FAN_IN;
    float a0 = 0.f, a1 = 0.f, a2 = 0.f, a3 = 0.f;
#pragma unroll 8
    for (int k = 0; k < FAN_IN; ++k) {
        const int src = edge_src[ebase + k] - SRCBASE;   // wave-uniform s_load
        const float w = weight[ebase + k];               // wave-uniform s_load
        const ushort4 v = *(const ushort4*)(sb + (size_t)src * 512);
        a0 = fmaf(w, bf2f(v.x), a0);
        a1 = fmaf(w, bf2f(v.y), a1);
        a2 = fmaf(w, bf2f(v.z), a2);
        a3 = fmaf(w, bf2f(v.w), a3);
    }
    const float bv = bias_l[node];
    a0 += bv; a1 += bv; a2 += bv; a3 += bv;
    float4 o; o.x = a0; o.y = a1; o.z = a2; o.w = a3;
    *(float4*)(raw + (size_t)node * 512 + bc * 256 + lane * 4) = o;

    cs[tid] = 0.f; cq[tid] = 0.f;
    __syncthreads();
    const int lb = lane * 4;
    atomicAdd(&cs[lb + 0], a0); atomicAdd(&cq[lb + 0], a0 * a0);
    atomicAdd(&cs[lb + 1], a1); atomicAdd(&cq[lb + 1], a1 * a1);
    atomicAdd(&cs[lb + 2], a2); atomicAdd(&cq[lb + 2], a2 * a2);
    atomicAdd(&cs[lb + 3], a3); atomicAdd(&cq[lb + 3], a3 * a3);
    __syncthreads();
    atomicAdd(&gcs[bc * 256 + tid], cs[tid]);
    atomicAdd(&gcq[bc * 256 + tid], cq[tid]);
}

// ---------------------------------------------------------------------------
// LN apply + ReLU + bf16 pack: raw[M][512] f32 -> actT[M][512] bf16.
// Stats per batch column from the atomically-accumulated colsum/colsumsq.
template <int M>
__global__ __launch_bounds__(256) void lnapplyk(
    const float* __restrict__ raw, const float* __restrict__ gcs,
    const float* __restrict__ gcq, const float* __restrict__ gamma_l,
    const float* __restrict__ beta_l, u16* __restrict__ actT) {
    const int tid = threadIdx.x;
    const int b0 = tid * 2;
    const float inv = 1.f / (float)M;
    const float m0 = gcs[b0] * inv, m1 = gcs[b0 + 1] * inv;
    const float r0 = rsqrtf(gcq[b0] * inv - m0 * m0 + EPS);
    const float r1 = rsqrtf(gcq[b0 + 1] * inv - m1 * m1 + EPS);
    for (int row = blockIdx.x; row < M; row += 256) {
        const float2 v = *(const float2*)(raw + (size_t)row * 512 + b0);
        const float g = gamma_l[row], bt = beta_l[row];   // uniform s_load
        const float o0 = fmaxf(fmaf(g * (v.x - m0), r0, bt), 0.f);
        const float o1 = fmaxf(fmaf(g * (v.y - m1), r1, bt), 0.f);
        *(u32*)(actT + (size_t)row * 512 + b0) =
            (u32)f2bf(o0) | ((u32)f2bf(o1) << 16);
    }
}

// ---------------------------------------------------------------------------
// Output layer: 2 targets x 128 edges, reading PRE-LN raw3 + stats3 and
// applying LN+ReLU inline (removes the LN3-apply kernel entirely).
__global__ __launch_bounds__(256) void outk(
    const float* __restrict__ raw3, const float* __restrict__ gcs,
    const float* __restrict__ gcq, const float* __restrict__ weight,
    const int* __restrict__ edge_src, const float* __restrict__ gamma_l,
    const float* __restrict__ beta_l, const float* __restrict__ bias_o,
    float* __restrict__ out) {
    const int tid = threadIdx.x, bid = blockIdx.x;
    const int tgt = __builtin_amdgcn_readfirstlane(tid >> 7);  // wave-uniform
    const int b = bid * 128 + (tid & 127);
    const float inv = 1.f / 512.f;
    const float mb = gcs[b] * inv;
    const float rb = rsqrtf(gcq[b] * inv - mb * mb + EPS);
    const int ebase = 458752 + tgt * FAN_IN;
    float acc = 0.f;
#pragma unroll 8
    for (int k = 0; k < FAN_IN; ++k) {
        const int src = edge_src[ebase + k] - 7168;      // wave-uniform s_load
        const float w = weight[ebase + k];
        const float g = gamma_l[src], bt = beta_l[src];
        const float v = raw3[(size_t)src * 512 + b];
        acc = fmaf(w, fmaxf(fmaf(g * (v - mb), rb, bt), 0.f), acc);
    }
    out[(size_t)b * 2 + tgt] = acc + bias_o[tgt];
}

// ---------------------------------------------------------------------------
extern "C" void kernel_launch(void* const* d_in, const int* in_sizes, int n_in,
                              void* d_out, int out_size, void* d_ws, size_t ws_size,
                              hipStream_t stream) {
    const float* x        = (const float*)d_in[0];
    const float* weight   = (const float*)d_in[1];
    const float* bias     = (const float*)d_in[2];
    const float* ln_gamma = (const float*)d_in[3];
    const float* ln_beta  = (const float*)d_in[4];
    const int*   edge_src = (const int*)d_in[5];
    float* out = (float*)d_out;

    // ws layout (all feature-major [node][512]):
    u16* xT    = (u16*)d_ws;                       // [4096][512] bf16   4 MB
    u16* actT1 = xT + (size_t)4096 * 512;          // [2048][512] bf16   2 MB
    u16* actT2 = actT1 + (size_t)2048 * 512;       // [1024][512] bf16   1 MB
    float* raw1 = (float*)(actT2 + (size_t)1024 * 512);  // [2048][512] f32
    float* raw2 = raw1 + (size_t)2048 * 512;             // [1024][512] f32
    float* raw3 = raw2 + (size_t)1024 * 512;             // [512][512]  f32
    float* stats = raw3 + (size_t)512 * 512;             // 3 x (cs512,cq512)

    // K0: x transpose -> bf16 feature-major; zero stats buffers
    prepk<<<513, 256, 0, stream>>>(x, xT, stats);
    // K1: layer1 gather (2048 nodes), raw1 + stats1
    gatherk<2048, 0, 0><<<1024, 256, 0, stream>>>(
        xT, weight, edge_src, bias, raw1, stats, stats + 512);
    // K2: LN1 -> actT1 bf16
    lnapplyk<2048><<<256, 256, 0, stream>>>(
        raw1, stats, stats + 512, ln_gamma, ln_beta, actT1);
    // K3: layer2 gather (1024 nodes)
    gatherk<1024, 262144, 4096><<<512, 256, 0, stream>>>(
        actT1, weight, edge_src, bias + 2048, raw2, stats + 1024, stats + 1536);
    // K4: LN2 -> actT2 bf16
    lnapplyk<1024><<<256, 256, 0, stream>>>(
        raw2, stats + 1024, stats + 1536, ln_gamma + 2048, ln_beta + 2048, actT2);
    // K5: layer3 gather (512 nodes) -> raw3 + stats3 (no LN-apply pass needed)
    gatherk<512, 393216, 6144><<<256, 256, 0, stream>>>(
        actT2, weight, edge_src, bias + 3072, raw3, stats + 2048, stats + 2560);
    // K6: output layer with LN3 applied inline -> d_out [512][2]
    outk<<<4, 256, 0, stream>>>(
        raw3, stats + 2048, stats + 2560, weight, edge_src,
        ln_gamma + 3072, ln_beta + 3072, bias + 3584, out);
}

// Round 2
// 153.574 us; speedup vs baseline: 1.0336x; 1.0336x over previous
//
#include <hip/hip_runtime.h>

// LAYER_IDX = [0, 4096, 6144, 7168, 7680, 7682]
// L1: 4096->2048 ebase 0       | L2: 2048->1024 ebase 262144
// L3: 1024->512  ebase 393216  | out: 512->2    ebase 458752
// Sparse gather formulation, LN fused into the consumer of each layer.
// LN stats accumulate into 16 shadow copies to cut same-address atomic
// contention (deepest chain 512 -> 32); consumers fold the shadows.
#define BATCH 512
#define FAN_IN 128
#define EPS 1e-5f
#define NSHADOW 16

typedef unsigned short u16;
typedef unsigned int u32;

__device__ __forceinline__ u16 f2bf(float f) {   // fp32->bf16 RNE
    union { float f; u32 u; } v; v.f = f;
    u32 r = v.u + 0x7fffu + ((v.u >> 16) & 1u);
    return (u16)(r >> 16);
}
__device__ __forceinline__ float bf2f(u16 h) {
    union { u32 u; float f; } v; v.u = ((u32)h) << 16; return v.f;
}

// ---------------------------------------------------------------------------
// K0: transpose x[512][4096] f32 -> xT[4096][512] bf16 (blocks 0..511).
// Blocks 512..527 zero the 3 x [16][2][512] shadow-stats buffers.
__global__ __launch_bounds__(256) void prepk(
    const float* __restrict__ x, u16* __restrict__ xT,
    float* __restrict__ stats) {
    const int tid = threadIdx.x, bid = blockIdx.x;
    if (bid >= 512) {
        const int z0 = (bid - 512) * 3072;       // 16 blocks x 3072 = 49152
        for (int i = tid; i < 3072; i += 256) stats[z0 + i] = 0.f;
        return;
    }
    __shared__ float T[64][65];                  // +1 pad: conflict-free cols
    const int f0 = (bid & 63) * 64, b0 = (bid >> 6) * 64;
    const int r = tid >> 4, c4 = (tid & 15) * 4;
#pragma unroll
    for (int rr = 0; rr < 4; ++rr) {
        const int row = r + rr * 16;
        const float4 v = *(const float4*)(x + (size_t)(b0 + row) * 4096 + f0 + c4);
        T[row][c4] = v.x; T[row][c4 + 1] = v.y;
        T[row][c4 + 2] = v.z; T[row][c4 + 3] = v.w;
    }
    __syncthreads();
#pragma unroll
    for (int half = 0; half < 2; ++half) {
        const int fr = (tid >> 3) + half * 32;
        const int bq = (tid & 7) * 8;
        uint4 pk;
        pk.x = (u32)f2bf(T[bq + 0][fr]) | ((u32)f2bf(T[bq + 1][fr]) << 16);
        pk.y = (u32)f2bf(T[bq + 2][fr]) | ((u32)f2bf(T[bq + 3][fr]) << 16);
        pk.z = (u32)f2bf(T[bq + 4][fr]) | ((u32)f2bf(T[bq + 5][fr]) << 16);
        pk.w = (u32)f2bf(T[bq + 6][fr]) | ((u32)f2bf(T[bq + 7][fr]) << 16);
        *(uint4*)(xT + (size_t)(f0 + fr) * 512 + b0 + bq) = pk;
    }
}

// ---------------------------------------------------------------------------
// K1: layer-1 gather. Wave = (node, batch-half of 256); block = 4 node-waves.
// bid%8 -> XCD heuristic keeps each half's 2 MB xT panel XCD-local.
// Epilogue: +bias, write raw1 f32, LDS col-reduce, shadow-atomic stats.
__global__ __launch_bounds__(256) void gather1(
    const u16* __restrict__ xT, const float* __restrict__ weight,
    const int* __restrict__ edge_src, const float* __restrict__ bias_l,
    float* __restrict__ raw1, float* __restrict__ stats1) {
    __shared__ float cs[256];
    __shared__ float cq[256];
    const int tid = threadIdx.x, bid = blockIdx.x;
    const int rr = bid & 7;
    const int bc = rr >> 2;                      // batch half
    const int ng = (bid >> 3) * 4 + (rr & 3);    // node group [0,512)
    const int shadow = (bid >> 3) & (NSHADOW - 1);
    const int wave = __builtin_amdgcn_readfirstlane(tid >> 6);
    const int lane = tid & 63;
    const int node = ng * 4 + wave;
    const u16* sb = xT + bc * 256 + lane * 4;
    const int ebase = node * FAN_IN;
    float a0 = 0.f, a1 = 0.f, a2 = 0.f, a3 = 0.f;
#pragma unroll 16
    for (int k = 0; k < FAN_IN; ++k) {
        const int src = edge_src[ebase + k];     // wave-uniform s_load
        const float w = weight[ebase + k];
        const ushort4 v = *(const ushort4*)(sb + (size_t)src * 512);
        a0 = fmaf(w, bf2f(v.x), a0);
        a1 = fmaf(w, bf2f(v.y), a1);
        a2 = fmaf(w, bf2f(v.z), a2);
        a3 = fmaf(w, bf2f(v.w), a3);
    }
    const float bv = bias_l[node];
    a0 += bv; a1 += bv; a2 += bv; a3 += bv;
    float4 o; o.x = a0; o.y = a1; o.z = a2; o.w = a3;
    *(float4*)(raw1 + (size_t)node * 512 + bc * 256 + lane * 4) = o;

    cs[tid] = 0.f; cq[tid] = 0.f;
    __syncthreads();
    const int lb = lane * 4;
    atomicAdd(&cs[lb + 0], a0); atomicAdd(&cq[lb + 0], a0 * a0);
    atomicAdd(&cs[lb + 1], a1); atomicAdd(&cq[lb + 1], a1 * a1);
    atomicAdd(&cs[lb + 2], a2); atomicAdd(&cq[lb + 2], a2 * a2);
    atomicAdd(&cs[lb + 3], a3); atomicAdd(&cq[lb + 3], a3 * a3);
    __syncthreads();
    float* gs = stats1 + shadow * 1024;          // [16][2][512]
    atomicAdd(&gs[bc * 256 + tid], cs[tid]);
    atomicAdd(&gs[512 + bc * 256 + tid], cq[tid]);
}

// ---------------------------------------------------------------------------
// K2/K3: fused gather: applies source-layer LN+ReLU on the fly from rawS +
// folded shadow stats, accumulates target pre-activations, emits rawT +
// target shadow stats. Wave = (node, batch-quarter of 128): 2 cols/lane.
template <int EBASE, int SRCBASE, int MSRC>
__global__ __launch_bounds__(256) void gatherF(
    const float* __restrict__ rawS, const float* __restrict__ statsS,
    const float* __restrict__ gammaS, const float* __restrict__ betaS,
    const float* __restrict__ weight, const int* __restrict__ edge_src,
    const float* __restrict__ bias_l, float* __restrict__ rawT,
    float* __restrict__ statsT) {
    __shared__ float cs[128];
    __shared__ float cq[128];
    const int tid = threadIdx.x, bid = blockIdx.x;
    const int qc = bid & 3;                      // batch quarter
    const int ng = bid >> 2;                     // node group
    const int shadow = ng & (NSHADOW - 1);
    const int wave = __builtin_amdgcn_readfirstlane(tid >> 6);
    const int lane = tid & 63;
    const int node = ng * 4 + wave;
    const int c0 = qc * 128 + lane * 2;

    // fold source-layer shadow stats for this lane's two columns
    float cs0 = 0.f, cs1 = 0.f, qs0 = 0.f, qs1 = 0.f;
#pragma unroll
    for (int s = 0; s < NSHADOW; ++s) {
        const float2 c = *(const float2*)(statsS + s * 1024 + c0);
        const float2 q = *(const float2*)(statsS + s * 1024 + 512 + c0);
        cs0 += c.x; cs1 += c.y; qs0 += q.x; qs1 += q.y;
    }
    const float inv = 1.f / (float)MSRC;
    const float m0 = cs0 * inv, m1 = cs1 * inv;
    const float r0 = rsqrtf(qs0 * inv - m0 * m0 + EPS);
    const float r1 = rsqrtf(qs1 * inv - m1 * m1 + EPS);

    const float* sb = rawS + c0;
    const int ebase = EBASE + node * FAN_IN;
    float a0 = 0.f, a1 = 0.f;
#pragma unroll 8
    for (int k = 0; k < FAN_IN; ++k) {
        const int src = edge_src[ebase + k] - SRCBASE;  // wave-uniform
        const float w = weight[ebase + k];
        const float g = gammaS[src], bt = betaS[src];   // wave-uniform
        const float2 v = *(const float2*)(sb + (size_t)src * 512);
        const float x0 = fmaxf(fmaf(g * (v.x - m0), r0, bt), 0.f);
        const float x1 = fmaxf(fmaf(g * (v.y - m1), r1, bt), 0.f);
        a0 = fmaf(w, x0, a0);
        a1 = fmaf(w, x1, a1);
    }
    const float bv = bias_l[node];
    a0 += bv; a1 += bv;
    float2 o; o.x = a0; o.y = a1;
    *(float2*)(rawT + (size_t)node * 512 + c0) = o;

    if (tid < 128) { cs[tid] = 0.f; cq[tid] = 0.f; }
    __syncthreads();
    const int lb = lane * 2;
    atomicAdd(&cs[lb + 0], a0); atomicAdd(&cq[lb + 0], a0 * a0);
    atomicAdd(&cs[lb + 1], a1); atomicAdd(&cq[lb + 1], a1 * a1);
    __syncthreads();
    float* gs = statsT + shadow * 1024;
    if (tid < 128)      atomicAdd(&gs[qc * 128 + tid], cs[tid]);
    else                atomicAdd(&gs[512 + qc * 128 + (tid - 128)], cq[tid - 128]);
}

// ---------------------------------------------------------------------------
// K4: output layer (2 targets x 128 edges), LN3 applied inline from raw3 +
// folded shadow stats.
__global__ __launch_bounds__(256) void outk(
    const float* __restrict__ raw3, const float* __restrict__ stats3,
    const float* __restrict__ weight, const int* __restrict__ edge_src,
    const float* __restrict__ gammaS, const float* __restrict__ betaS,
    const float* __restrict__ bias_o, float* __restrict__ out) {
    const int tid = threadIdx.x, bid = blockIdx.x;
    const int tgt = __builtin_amdgcn_readfirstlane(tid >> 7);  // wave-uniform
    const int b = bid * 128 + (tid & 127);
    float csum = 0.f, qsum = 0.f;
#pragma unroll
    for (int s = 0; s < NSHADOW; ++s) {
        csum += stats3[s * 1024 + b];
        qsum += stats3[s * 1024 + 512 + b];
    }
    const float inv = 1.f / 512.f;
    const float mb = csum * inv;
    const float rb = rsqrtf(qsum * inv - mb * mb + EPS);
    const int ebase = 458752 + tgt * FAN_IN;
    float acc = 0.f;
#pragma unroll 8
    for (int k = 0; k < FAN_IN; ++k) {
        const int src = edge_src[ebase + k] - 7168;      // wave-uniform
        const float w = weight[ebase + k];
        const float g = gammaS[src], bt = betaS[src];
        const float v = raw3[(size_t)src * 512 + b];
        acc = fmaf(w, fmaxf(fmaf(g * (v - mb), rb, bt), 0.f), acc);
    }
    out[(size_t)b * 2 + tgt] = acc + bias_o[tgt];
}

// ---------------------------------------------------------------------------
extern "C" void kernel_launch(void* const* d_in, const int* in_sizes, int n_in,
                              void* d_out, int out_size, void* d_ws, size_t ws_size,
                              hipStream_t stream) {
    const float* x        = (const float*)d_in[0];
    const float* weight   = (const float*)d_in[1];
    const float* bias     = (const float*)d_in[2];
    const float* ln_gamma = (const float*)d_in[3];
    const float* ln_beta  = (const float*)d_in[4];
    const int*   edge_src = (const int*)d_in[5];
    float* out = (float*)d_out;

    u16* xT = (u16*)d_ws;                                // [4096][512] bf16
    float* raw1 = (float*)(xT + (size_t)4096 * 512);     // [2048][512] f32
    float* raw2 = raw1 + (size_t)2048 * 512;             // [1024][512] f32
    float* raw3 = raw2 + (size_t)1024 * 512;             // [512][512]  f32
    float* stats = raw3 + (size_t)512 * 512;             // 3 x [16][2][512]
    float* stats1 = stats, *stats2 = stats + 16384, *stats3 = stats + 32768;

    // K0: transpose x -> bf16 feature-major; zero shadow stats
    prepk<<<528, 256, 0, stream>>>(x, xT, stats);
    // K1: layer1 gather -> raw1 + stats1
    gather1<<<1024, 256, 0, stream>>>(xT, weight, edge_src, bias, raw1, stats1);
    // K2: layer2 gather with LN1 fused -> raw2 + stats2
    gatherF<262144, 4096, 2048><<<1024, 256, 0, stream>>>(
        raw1, stats1, ln_gamma, ln_beta, weight, edge_src,
        bias + 2048, raw2, stats2);
    // K3: layer3 gather with LN2 fused -> raw3 + stats3
    gatherF<393216, 6144, 1024><<<512, 256, 0, stream>>>(
        raw2, stats2, ln_gamma + 2048, ln_beta + 2048, weight, edge_src,
        bias + 3072, raw3, stats3);
    // K4: output layer with LN3 fused -> d_out [512][2]
    outk<<<4, 256, 0, stream>>>(
        raw3, stats3, weight, edge_src,
        ln_gamma + 3072, ln_beta + 3072, bias + 3584, out);
}

// Round 3
// 151.297 us; speedup vs baseline: 1.0492x; 1.0151x over previous
//
#include <hip/hip_runtime.h>

// LAYER_IDX = [0, 4096, 6144, 7168, 7680, 7682]
// L1: 4096->2048 ebase 0       | L2: 2048->1024 ebase 262144
// L3: 1024->512  ebase 393216  | out: 512->2    ebase 458752
// Sparse gather formulation, LN fused into the consumer of each layer.
// v3: per-wave edge lists staged in LDS (one coalesced load) so the gather
// loop has NO per-iteration dependent edge-list load -> 16 independent
// gather loads in flight per unroll group (breaks the serial latency chain).
#define BATCH 512
#define FAN_IN 128
#define EPS 1e-5f
#define NSHADOW 16

typedef unsigned short u16;
typedef unsigned int u32;

__device__ __forceinline__ u16 f2bf(float f) {   // fp32->bf16 RNE
    union { float f; u32 u; } v; v.f = f;
    u32 r = v.u + 0x7fffu + ((v.u >> 16) & 1u);
    return (u16)(r >> 16);
}
__device__ __forceinline__ float bf2f(u16 h) {
    union { u32 u; float f; } v; v.u = ((u32)h) << 16; return v.f;
}

// ---------------------------------------------------------------------------
// K0: transpose x[512][4096] f32 -> xT[4096][512] bf16 (blocks 0..511).
// Blocks 512..527 zero the 3 x [16][2][512] shadow-stats buffers.
__global__ __launch_bounds__(256) void prepk(
    const float* __restrict__ x, u16* __restrict__ xT,
    float* __restrict__ stats) {
    const int tid = threadIdx.x, bid = blockIdx.x;
    if (bid >= 512) {
        const int z0 = (bid - 512) * 3072;
        for (int i = tid; i < 3072; i += 256) stats[z0 + i] = 0.f;
        return;
    }
    __shared__ float T[64][65];
    const int f0 = (bid & 63) * 64, b0 = (bid >> 6) * 64;
    const int r = tid >> 4, c4 = (tid & 15) * 4;
#pragma unroll
    for (int rr = 0; rr < 4; ++rr) {
        const int row = r + rr * 16;
        const float4 v = *(const float4*)(x + (size_t)(b0 + row) * 4096 + f0 + c4);
        T[row][c4] = v.x; T[row][c4 + 1] = v.y;
        T[row][c4 + 2] = v.z; T[row][c4 + 3] = v.w;
    }
    __syncthreads();
#pragma unroll
    for (int half = 0; half < 2; ++half) {
        const int fr = (tid >> 3) + half * 32;
        const int bq = (tid & 7) * 8;
        uint4 pk;
        pk.x = (u32)f2bf(T[bq + 0][fr]) | ((u32)f2bf(T[bq + 1][fr]) << 16);
        pk.y = (u32)f2bf(T[bq + 2][fr]) | ((u32)f2bf(T[bq + 3][fr]) << 16);
        pk.z = (u32)f2bf(T[bq + 4][fr]) | ((u32)f2bf(T[bq + 5][fr]) << 16);
        pk.w = (u32)f2bf(T[bq + 6][fr]) | ((u32)f2bf(T[bq + 7][fr]) << 16);
        *(uint4*)(xT + (size_t)(f0 + fr) * 512 + b0 + bq) = pk;
    }
}

// ---------------------------------------------------------------------------
// K1: layer-1 gather. Wave = (node, batch-quarter of 128 cols, ushort2/lane).
// 2048 blocks x 4 waves = 8192 waves (8/SIMD). bid&7 pairs -> XCD locality.
__global__ __launch_bounds__(256) void gather1(
    const u16* __restrict__ xT, const float* __restrict__ weight,
    const int* __restrict__ edge_src, const float* __restrict__ bias_l,
    float* __restrict__ raw1, float* __restrict__ stats1) {
    __shared__ int2 eL[4][FAN_IN];               // {byteoff, w_bits}
    __shared__ float cs[128], cq[128];
    const int tid = threadIdx.x, bid = blockIdx.x;
    const int qc = (bid & 7) >> 1;               // batch quarter
    const int ng = (bid >> 3) * 2 + (bid & 1);   // [0,512)
    const int shadow = ng & (NSHADOW - 1);
    const int wave = __builtin_amdgcn_readfirstlane(tid >> 6);
    const int lane = tid & 63;
    const int node = ng * 4 + wave;
    const int ebase = node * FAN_IN;

    {   // stage this wave's edge list: 2 edges/lane, one int2+float2 load
        const int2 s2 = *(const int2*)(edge_src + ebase + lane * 2);
        const float2 w2 = *(const float2*)(weight + ebase + lane * 2);
        int4 ent;
        ent.x = s2.x * 1024;                     // row byte offset (bf16 row)
        ent.y = __float_as_int(w2.x);
        ent.z = s2.y * 1024;
        ent.w = __float_as_int(w2.y);
        *(int4*)(&eL[wave][lane * 2]) = ent;     // ds_write_b128
    }
    const char* sb = (const char*)xT + qc * 256 + lane * 4;
    float a0 = 0.f, a1 = 0.f;
#pragma unroll 16
    for (int k = 0; k < FAN_IN; ++k) {
        const int2 e = eL[wave][k];              // uniform broadcast ds_read
        const float w = __int_as_float(e.y);
        const ushort2 v = *(const ushort2*)(sb + e.x);
        a0 = fmaf(w, bf2f(v.x), a0);
        a1 = fmaf(w, bf2f(v.y), a1);
    }
    const float bv = bias_l[node];
    a0 += bv; a1 += bv;
    const int c0 = qc * 128 + lane * 2;
    float2 o; o.x = a0; o.y = a1;
    *(float2*)(raw1 + (size_t)node * 512 + c0) = o;

    if (tid < 128) { cs[tid] = 0.f; cq[tid] = 0.f; }
    __syncthreads();
    const int lb = lane * 2;
    atomicAdd(&cs[lb], a0);     atomicAdd(&cq[lb], a0 * a0);
    atomicAdd(&cs[lb + 1], a1); atomicAdd(&cq[lb + 1], a1 * a1);
    __syncthreads();
    float* gs = stats1 + shadow * 1024;
    if (tid < 128) atomicAdd(&gs[qc * 128 + tid], cs[tid]);
    else           atomicAdd(&gs[512 + qc * 128 + (tid - 128)], cq[tid - 128]);
}

// ---------------------------------------------------------------------------
// K2: layer-2 gather with LN1 fused. Wave = (node, quarter, float2/lane).
// Edge list staged as {byteoff, w, gamma, beta} (16B/edge).
__global__ __launch_bounds__(256) void gather2(
    const float* __restrict__ raw1, const float* __restrict__ stats1,
    const float* __restrict__ gammaS, const float* __restrict__ betaS,
    const float* __restrict__ weight, const int* __restrict__ edge_src,
    const float* __restrict__ bias_l, float* __restrict__ raw2,
    float* __restrict__ stats2) {
    __shared__ int4 eL[4][FAN_IN];
    __shared__ float cs[128], cq[128];
    const int tid = threadIdx.x, bid = blockIdx.x;
    const int qc = (bid & 7) >> 1;
    const int ng = (bid >> 3) * 2 + (bid & 1);   // [0,256)
    const int shadow = ng & (NSHADOW - 1);
    const int wave = __builtin_amdgcn_readfirstlane(tid >> 6);
    const int lane = tid & 63;
    const int node = ng * 4 + wave;              // [0,1024)
    const int ebase = 262144 + node * FAN_IN;

    {
        const int2 s2 = *(const int2*)(edge_src + ebase + lane * 2);
        const float2 w2 = *(const float2*)(weight + ebase + lane * 2);
        const int r0 = s2.x - 4096, r1 = s2.y - 4096;
        int4 e0, e1;
        e0.x = r0 * 2048; e0.y = __float_as_int(w2.x);
        e0.z = __float_as_int(gammaS[r0]); e0.w = __float_as_int(betaS[r0]);
        e1.x = r1 * 2048; e1.y = __float_as_int(w2.y);
        e1.z = __float_as_int(gammaS[r1]); e1.w = __float_as_int(betaS[r1]);
        eL[wave][lane * 2] = e0;
        eL[wave][lane * 2 + 1] = e1;
    }

    const int c0 = qc * 128 + lane * 2;          // fold source LN stats
    float cs0 = 0.f, cs1 = 0.f, qs0 = 0.f, qs1 = 0.f;
#pragma unroll
    for (int s = 0; s < NSHADOW; ++s) {
        const float2 c = *(const float2*)(stats1 + s * 1024 + c0);
        const float2 q = *(const float2*)(stats1 + s * 1024 + 512 + c0);
        cs0 += c.x; cs1 += c.y; qs0 += q.x; qs1 += q.y;
    }
    const float inv = 1.f / 2048.f;
    const float m0 = cs0 * inv, m1 = cs1 * inv;
    const float r0_ = rsqrtf(qs0 * inv - m0 * m0 + EPS);
    const float r1_ = rsqrtf(qs1 * inv - m1 * m1 + EPS);

    const char* sb = (const char*)raw1 + qc * 512 + lane * 8;
    float a0 = 0.f, a1 = 0.f;
#pragma unroll 16
    for (int k = 0; k < FAN_IN; ++k) {
        const int4 e = eL[wave][k];
        const float w = __int_as_float(e.y);
        const float g = __int_as_float(e.z);
        const float bt = __int_as_float(e.w);
        const float2 v = *(const float2*)(sb + e.x);
        const float x0 = fmaxf(fmaf(g * (v.x - m0), r0_, bt), 0.f);
        const float x1 = fmaxf(fmaf(g * (v.y - m1), r1_, bt), 0.f);
        a0 = fmaf(w, x0, a0);
        a1 = fmaf(w, x1, a1);
    }
    const float bv = bias_l[node];
    a0 += bv; a1 += bv;
    float2 o; o.x = a0; o.y = a1;
    *(float2*)(raw2 + (size_t)node * 512 + c0) = o;

    if (tid < 128) { cs[tid] = 0.f; cq[tid] = 0.f; }
    __syncthreads();
    const int lb = lane * 2;
    atomicAdd(&cs[lb], a0);     atomicAdd(&cq[lb], a0 * a0);
    atomicAdd(&cs[lb + 1], a1); atomicAdd(&cq[lb + 1], a1 * a1);
    __syncthreads();
    float* gs = stats2 + shadow * 1024;
    if (tid < 128) atomicAdd(&gs[qc * 128 + tid], cs[tid]);
    else           atomicAdd(&gs[512 + qc * 128 + (tid - 128)], cq[tid - 128]);
}

// ---------------------------------------------------------------------------
// K3: layer-3 gather with LN2 fused. Wave = (node, eighth of 64 cols, 1/lane).
// 1024 blocks x 4 waves = 4096 waves. bid&7 -> direct XCD map.
__global__ __launch_bounds__(256) void gather3(
    const float* __restrict__ raw2, const float* __restrict__ stats2,
    const float* __restrict__ gammaS, const float* __restrict__ betaS,
    const float* __restrict__ weight, const int* __restrict__ edge_src,
    const float* __restrict__ bias_l, float* __restrict__ raw3,
    float* __restrict__ stats3) {
    __shared__ int4 eL[4][FAN_IN];
    __shared__ float cs[64], cq[64];
    const int tid = threadIdx.x, bid = blockIdx.x;
    const int ec = bid & 7;                      // batch eighth
    const int ng = bid >> 3;                     // [0,128)
    const int shadow = ng & (NSHADOW - 1);
    const int wave = __builtin_amdgcn_readfirstlane(tid >> 6);
    const int lane = tid & 63;
    const int node = ng * 4 + wave;              // [0,512)
    const int ebase = 393216 + node * FAN_IN;

    {
        const int2 s2 = *(const int2*)(edge_src + ebase + lane * 2);
        const float2 w2 = *(const float2*)(weight + ebase + lane * 2);
        const int r0 = s2.x - 6144, r1 = s2.y - 6144;
        int4 e0, e1;
        e0.x = r0 * 2048; e0.y = __float_as_int(w2.x);
        e0.z = __float_as_int(gammaS[r0]); e0.w = __float_as_int(betaS[r0]);
        e1.x = r1 * 2048; e1.y = __float_as_int(w2.y);
        e1.z = __float_as_int(gammaS[r1]); e1.w = __float_as_int(betaS[r1]);
        eL[wave][lane * 2] = e0;
        eL[wave][lane * 2 + 1] = e1;
    }

    const int c = ec * 64 + lane;
    float csum = 0.f, qsum = 0.f;
#pragma unroll
    for (int s = 0; s < NSHADOW; ++s) {
        csum += stats2[s * 1024 + c];
        qsum += stats2[s * 1024 + 512 + c];
    }
    const float inv = 1.f / 1024.f;
    const float m = csum * inv;
    const float rs = rsqrtf(qsum * inv - m * m + EPS);

    const char* sb = (const char*)raw2 + ec * 256 + lane * 4;
    float a = 0.f;
#pragma unroll 16
    for (int k = 0; k < FAN_IN; ++k) {
        const int4 e = eL[wave][k];
        const float v = *(const float*)(sb + e.x);
        const float g = __int_as_float(e.z);
        const float bt = __int_as_float(e.w);
        const float x = fmaxf(fmaf(g * (v - m), rs, bt), 0.f);
        a = fmaf(__int_as_float(e.y), x, a);
    }
    a += bias_l[node];
    raw3[(size_t)node * 512 + c] = a;

    if (tid < 64) { cs[tid] = 0.f; cq[tid] = 0.f; }
    __syncthreads();
    atomicAdd(&cs[lane], a); atomicAdd(&cq[lane], a * a);
    __syncthreads();
    float* gs = stats3 + shadow * 1024;
    if (tid < 64)       atomicAdd(&gs[ec * 64 + tid], cs[tid]);
    else if (tid < 128) atomicAdd(&gs[512 + ec * 64 + (tid - 64)], cq[tid - 64]);
}

// ---------------------------------------------------------------------------
// K4: output layer, LN3 fused, edge lists staged in LDS (same anti-latency fix).
__global__ __launch_bounds__(256) void outk(
    const float* __restrict__ raw3, const float* __restrict__ stats3,
    const float* __restrict__ weight, const int* __restrict__ edge_src,
    const float* __restrict__ gammaS, const float* __restrict__ betaS,
    const float* __restrict__ bias_o, float* __restrict__ out) {
    __shared__ int4 eL[2][FAN_IN];
    const int tid = threadIdx.x, bid = blockIdx.x;
    const int half = tid >> 7;                   // target index
    const int hb = tid & 127;
    {
        const int ebase = 458752 + half * FAN_IN;
        const int s = edge_src[ebase + hb] - 7168;
        int4 e;
        e.x = s * 2048;
        e.y = __float_as_int(weight[ebase + hb]);
        e.z = __float_as_int(gammaS[s]);
        e.w = __float_as_int(betaS[s]);
        eL[half][hb] = e;
    }
    __syncthreads();                             // cross-wave staging
    const int b = bid * 128 + hb;
    float csum = 0.f, qsum = 0.f;
#pragma unroll
    for (int s = 0; s < NSHADOW; ++s) {
        csum += stats3[s * 1024 + b];
        qsum += stats3[s * 1024 + 512 + b];
    }
    const float inv = 1.f / 512.f;
    const float mb = csum * inv;
    const float rb = rsqrtf(qsum * inv - mb * mb + EPS);
    const char* sb = (const char*)raw3 + (size_t)b * 4;
    float acc = 0.f;
#pragma unroll 16
    for (int k = 0; k < FAN_IN; ++k) {
        const int4 e = eL[half][k];
        const float v = *(const float*)(sb + e.x);
        const float g = __int_as_float(e.z), bt = __int_as_float(e.w);
        const float x = fmaxf(fmaf(g * (v - mb), rb, bt), 0.f);
        acc = fmaf(__int_as_float(e.y), x, acc);
    }
    out[(size_t)b * 2 + half] = acc + bias_o[half];
}

// ---------------------------------------------------------------------------
extern "C" void kernel_launch(void* const* d_in, const int* in_sizes, int n_in,
                              void* d_out, int out_size, void* d_ws, size_t ws_size,
                              hipStream_t stream) {
    const float* x        = (const float*)d_in[0];
    const float* weight   = (const float*)d_in[1];
    const float* bias     = (const float*)d_in[2];
    const float* ln_gamma = (const float*)d_in[3];
    const float* ln_beta  = (const float*)d_in[4];
    const int*   edge_src = (const int*)d_in[5];
    float* out = (float*)d_out;

    u16* xT = (u16*)d_ws;                                // [4096][512] bf16
    float* raw1 = (float*)(xT + (size_t)4096 * 512);     // [2048][512] f32
    float* raw2 = raw1 + (size_t)2048 * 512;             // [1024][512] f32
    float* raw3 = raw2 + (size_t)1024 * 512;             // [512][512]  f32
    float* stats = raw3 + (size_t)512 * 512;             // 3 x [16][2][512]
    float* stats1 = stats, *stats2 = stats + 16384, *stats3 = stats + 32768;

    prepk<<<528, 256, 0, stream>>>(x, xT, stats);
    gather1<<<2048, 256, 0, stream>>>(xT, weight, edge_src, bias, raw1, stats1);
    gather2<<<1024, 256, 0, stream>>>(
        raw1, stats1, ln_gamma, ln_beta, weight, edge_src,
        bias + 2048, raw2, stats2);
    gather3<<<1024, 256, 0, stream>>>(
        raw2, stats2, ln_gamma + 2048, ln_beta + 2048, weight, edge_src,
        bias + 3072, raw3, stats3);
    outk<<<4, 256, 0, stream>>>(
        raw3, stats3, weight, edge_src,
        ln_gamma + 3072, ln_beta + 3072, bias + 3584, out);
}